// Round 12
// baseline (921.730 us; speedup 1.0000x reference)
//
#include <hip/hip_runtime.h>

typedef float f2 __attribute__((ext_vector_type(2)));
typedef float f4 __attribute__((ext_vector_type(4)));

#define TT 2048
#define BB 512
#define II 10
#define HH 20
#define CH 16                 // consumer steps per barrier / history depth
#define RS 32                 // ring slots = 2 chunks (double buffer)
#define NCHUNK (TT / CH)      // 128

#define LOG2E 1.44269504088896340736f

__device__ __forceinline__ float fexp2(float x) {
#if __has_builtin(__builtin_amdgcn_exp2f)
    return __builtin_amdgcn_exp2f(x);
#else
    return exp2f(x);
#endif
}

// One block = 2 waves, TWO samples (sA=2*blk, sB=2*blk+1).
// Wave 0 (consumer): SKEWED DUAL-SAMPLE scan. Lane layout per scan is R10's:
//   lanes 0..19 = forward dir, lanes 32..51 = reverse dir (lane owns hidden
//   unit j of its dir). Both samples use the SAME weight registers (weights
//   are sample-independent) -- only hb/xp/c/h are duplicated (~26 VGPRs).
//   Per iter: compA -> write h_A -> issue A's h/xp reads -> compB (hides A's
//   LDS round trip) -> write h_B -> issue B's reads (hide under next compA).
//   Per-sample-step issue count is unchanged vs R10; LDS RAW latency is
//   cross-hidden between the two scans (DS pipe in-order, counted lgkmcnt).
// Wave 1 (producer): xproj[t] for both samples/dirs into ring[32][2][64]
//   (double-buffered halves, 1 __syncthreads per 16 steps, 4x produce8/chunk).
// Chunk-end: staged 2 samples x 2 dirs x 16 x 20 h block dumped to HBM by all
// 64 lanes (10 q x 2 stores each), store vmcnt drain off the recurrence.
// Gate rows pre-scaled by -log2e (-2log2e for g) so sigma/tanh use v_exp_f32
// (2^x) directly; tanh via 2*sigma-1 in FMA form.
__global__ __launch_bounds__(128, 1) void lstm_bidir(
    const float* __restrict__ x,
    const float* __restrict__ w_ih_f, const float* __restrict__ w_hh_f,
    const float* __restrict__ b_ih_f, const float* __restrict__ b_hh_f,
    const float* __restrict__ w_ih_r, const float* __restrict__ w_hh_r,
    const float* __restrict__ b_ih_r, const float* __restrict__ b_hh_r,
    float* __restrict__ out)
{
    const int tid  = threadIdx.x;
    const int wid  = tid >> 6;     // 0 = consumer, 1 = producer
    const int lane = tid & 63;
    const int blk  = blockIdx.x;   // 0..255
    const int sA   = 2 * blk;
    const int sB   = 2 * blk + 1;

    const int  dirh  = lane >> 5;          // 0 = forward half, 1 = reverse half
    const int  hl    = lane & 31;
    const bool valid = (hl < HH);
    const int  j     = valid ? hl : (HH - 1);   // clamp keeps loads in-bounds

    // Row scale per gate (i,f,g,o): sigmoid rows -log2e, tanh row -2log2e.
    const float gsc[4] = { -LOG2E, -LOG2E, -2.0f * LOG2E, -LOG2E };

    __shared__ f4    ring[RS][2][64];        // [slot][sample][lane]
    __shared__ float hstage[2][CH][64];      // [sample][step-in-chunk][lane]

    const float* __restrict__ w_ih = dirh ? w_ih_r : w_ih_f;
    const float* __restrict__ w_hh = dirh ? w_hh_r : w_hh_f;
    const float* __restrict__ b_ih = dirh ? b_ih_r : b_ih_f;
    const float* __restrict__ b_hh = dirh ? b_hh_r : b_hh_f;

    const int t0    = dirh ? (TT - 1) : 0;
    const int xstep = dirh ? -(BB * II) : (BB * II);

    if (wid == 1) {
        // ---------------- producer wave (both samples, both halves) ----------------
        f2 wih[4][5];
        float bs[4];
#pragma unroll
        for (int g = 0; g < 4; ++g) {
            const int r = g * HH + j;
#pragma unroll
            for (int k = 0; k < 5; ++k) {
                f2 w = *(const f2*)(w_ih + r * II + 2 * k);
                wih[g][k] = w * gsc[g];
            }
            bs[g] = (b_ih[r] + b_hh[r]) * gsc[g];
        }
        const int xbaseA = (t0 * BB + sA) * II;
        const int xbaseB = xbaseA + II;      // sB = sA+1

        auto produce8 = [&](int sc, int xbase, int base) {
            f2 xb[8][5];
#pragma unroll
            for (int i = 0; i < 8; ++i) {
                int u = base + i; if (u > TT - 1) u = TT - 1;   // in-bounds clamp
                const float* px = x + (xbase + u * xstep);
#pragma unroll
                for (int k = 0; k < 5; ++k) xb[i][k] = *(const f2*)(px + 2 * k);
            }
#pragma unroll
            for (int i = 0; i < 8; ++i) {
                const int u = base + i;
                if (u < TT) {
                    f4 xp;
#pragma unroll
                    for (int g = 0; g < 4; ++g) {
                        f2 p = {bs[g], 0.f};
#pragma unroll
                        for (int k = 0; k < 5; ++k) p += wih[g][k] * xb[i][k];
                        xp[g] = p[0] + p[1];
                    }
                    ring[u & (RS - 1)][sc][lane] = xp;
                }
            }
        };

        produce8(0, xbaseA, 0); produce8(0, xbaseA, 8);     // prefill steps 0..15
        produce8(1, xbaseB, 0); produce8(1, xbaseB, 8);
        for (int chunk = 0; chunk < NCHUNK; ++chunk) {
            __syncthreads();
            const int base = (chunk + 1) * CH;   // fill next chunk's half
            produce8(0, xbaseA, base); produce8(0, xbaseA, base + 8);
            produce8(1, xbaseB, base); produce8(1, xbaseB, base + 8);
        }
    } else {
        // ------------- consumer wave: skewed dual-sample scan -------------
        __builtin_amdgcn_s_setprio(1);

        f2 whh[4][10];    // shared by BOTH samples (one (dir,unit) row set per lane)
#pragma unroll
        for (int g = 0; g < 4; ++g) {
            const int r = g * HH + j;
#pragma unroll
            for (int k = 0; k < 10; ++k) {
                f2 w = *(const f2*)(w_hh + r * HH + 2 * k);
                whh[g][k] = w * gsc[g];
            }
        }

        const int hboff = dirh * 32;   // own half's 20-float segment in hstage row

        auto comp = [&](const f4 (&hb)[5], const f4& xp, float& c, float& h) {
            f2 a0[4], a1[4];
#pragma unroll
            for (int g = 0; g < 4; ++g) { a0[g] = f2{xp[g], 0.f}; a1[g] = f2{0.f, 0.f}; }
#pragma unroll
            for (int k = 0; k < 5; ++k) {
                const f4 hv = hb[k];
                f2 lo; lo[0] = hv[0]; lo[1] = hv[1];
                f2 hi; hi[0] = hv[2]; hi[1] = hv[3];
#pragma unroll
                for (int g = 0; g < 4; ++g) {
                    a0[g] += whh[g][2 * k]     * lo;
                    a1[g] += whh[g][2 * k + 1] * hi;
                }
            }
            float u[4];
#pragma unroll
            for (int g = 0; g < 4; ++g) {
                const f2 a = a0[g] + a1[g];
                u[g] = a[0] + a[1];               // xp pre-seeded, exp2-ready
            }
            const float ig = __builtin_amdgcn_rcpf(1.0f + fexp2(u[0]));
            const float fg = __builtin_amdgcn_rcpf(1.0f + fexp2(u[1]));
            const float sg = __builtin_amdgcn_rcpf(1.0f + fexp2(u[2]));  // sigma(2 v_g)
            const float og = __builtin_amdgcn_rcpf(1.0f + fexp2(u[3]));
            const float i2 = ig + ig;
            const float o2 = og + og;
            const float m  = __builtin_fmaf(i2, sg, -ig);       // i * tanh(v_g)
            c = __builtin_fmaf(fg, c, m);
            const float sc_ = __builtin_amdgcn_rcpf(
                                1.0f + fexp2(c * (-2.0f * LOG2E)));  // sigma(2c)
            h = __builtin_fmaf(o2, sc_, -og);                   // o * tanh(c)
        };

        f4 hbA[5], hbB[5];
#pragma unroll
        for (int k = 0; k < 5; ++k) { hbA[k] = f4{0.f,0.f,0.f,0.f}; hbB[k] = f4{0.f,0.f,0.f,0.f}; }

        float cA = 0.f, hA = 0.f, cB = 0.f, hB = 0.f;
        int t = 0;

        for (int chunk = 0; chunk < NCHUNK; ++chunk) {
            __syncthreads();
            f4 xpA = ring[t & (RS - 1)][0][lane];
            f4 xpB = ring[t & (RS - 1)][1][lane];
#pragma unroll 4
            for (int i = 0; i < CH; ++i, ++t) {
                // ---- scan A step t ----
                comp(hbA, xpA, cA, hA);
                hstage[0][i][lane] = hA;
                __builtin_amdgcn_wave_barrier();
                // A's reads for t+1: latency hidden under compB
#pragma unroll
                for (int k = 0; k < 5; ++k)
                    hbA[k] = *(const f4*)&hstage[0][i][hboff + 4 * k];
                if (i < CH - 1) xpA = ring[(t + 1) & (RS - 1)][0][lane];

                // ---- scan B step t ----
                comp(hbB, xpB, cB, hB);
                hstage[1][i][lane] = hB;
                __builtin_amdgcn_wave_barrier();
                // B's reads for t+1: latency hidden under next iter's compA
#pragma unroll
                for (int k = 0; k < 5; ++k)
                    hbB[k] = *(const f4*)&hstage[1][i][hboff + 4 * k];
                if (i < CH - 1) xpB = ring[(t + 1) & (RS - 1)][1][lane];
            }

            // ---- dump both samples' 2x16x20 h blocks to HBM (off the chain) ----
            const int tbase = chunk * CH;
#pragma unroll
            for (int q = 0; q < 10; ++q) {
                const int idx = q * 64 + lane;       // 0..639 within a sample
                const int td  = idx / 40;            // 0..15
                const int r   = idx - td * 40;
                const int dd  = r / 20;              // 0 = fwd, 1 = rev
                const int jd  = r - dd * 20;         // 0..19
                const int tg  = tbase + td;
                const int trow = dd ? (TT - 1 - tg) : tg;
                const int oA = (trow * BB + sA) * (2 * HH) + dd * HH + jd;
                const float vA = hstage[0][td][dd * 32 + jd];
                const float vB = hstage[1][td][dd * 32 + jd];
                out[oA]            = vA;
                out[oA + 2 * HH]   = vB;     // sample sB = sA+1: +2H stride
            }
        }
    }
}

extern "C" void kernel_launch(void* const* d_in, const int* in_sizes, int n_in,
                              void* d_out, int out_size, void* d_ws, size_t ws_size,
                              hipStream_t stream) {
    const float* xp     = (const float*)d_in[0];
    const float* w_ih_f = (const float*)d_in[1];
    const float* w_hh_f = (const float*)d_in[2];
    const float* b_ih_f = (const float*)d_in[3];
    const float* b_hh_f = (const float*)d_in[4];
    const float* w_ih_r = (const float*)d_in[5];
    const float* w_hh_r = (const float*)d_in[6];
    const float* b_ih_r = (const float*)d_in[7];
    const float* b_hh_r = (const float*)d_in[8];
    float* outp = (float*)d_out;

    hipLaunchKernelGGL(lstm_bidir, dim3(256), dim3(128), 0, stream,
                       xp, w_ih_f, w_hh_f, b_ih_f, b_hh_f,
                       w_ih_r, w_hh_r, b_ih_r, b_hh_r, outp);
}

// Round 13
// 646.822 us; speedup vs baseline: 1.4250x; 1.4250x over previous
//
#include <hip/hip_runtime.h>

typedef float f2 __attribute__((ext_vector_type(2)));
typedef float f4 __attribute__((ext_vector_type(4)));

#define TT 2048
#define BB 512
#define II 10
#define HH 20
#define CH 16                 // output staging depth (dump every 16 steps)
#define NCHUNK (TT / CH)      // 128

#define LOG2E 1.44269504088896340736f

__device__ __forceinline__ float fexp2(float x) {
#if __has_builtin(__builtin_amdgcn_exp2f)
    return __builtin_amdgcn_exp2f(x);
#else
    return exp2f(x);
#endif
}

// ONE self-contained wave per (direction, sample): 1024 blocks x 64 threads
// = exactly 1 wave per SIMD. No producer wave, no __syncthreads, no ring.
// Lane j (j<20) owns hidden unit j and computes all 4 gate recurrent dots.
// Per step, after {ds_write h; ds_read hb x5}, the wave computes NEXT step's
// x-projection (~70cy of pk-FMAs independent of h) + x prefetch + rotation
// -- filling the ~130cy LDS round-trip that R10 left exposed.
// Output is staged in LDS (hstage[16][20]) and dumped to HBM every 16 steps
// by all 64 lanes (5 each), keeping store drains off the recurrence (R9).
// Gate rows pre-scaled by -log2e (-2log2e for g) so activations use
// v_exp_f32 (2^x) directly. Activation algebra in product-rcp form:
//   sigma(a)*tanh(b) = (1-e_b) * rcp((1+e_a)(1+e_b))   [5 exp2 + 3 rcp/step]
__global__ __launch_bounds__(64) void lstm_bidir(
    const float* __restrict__ x,
    const float* __restrict__ w_ih_f, const float* __restrict__ w_hh_f,
    const float* __restrict__ b_ih_f, const float* __restrict__ b_hh_f,
    const float* __restrict__ w_ih_r, const float* __restrict__ w_hh_r,
    const float* __restrict__ b_ih_r, const float* __restrict__ b_hh_r,
    float* __restrict__ out)
{
    const int lane = threadIdx.x;
    const int blk  = blockIdx.x;
    const int dir  = blk >> 9;     // 0 = forward, 1 = reverse
    const int s    = blk & 511;    // batch sample

    const float* __restrict__ w_ih = dir ? w_ih_r : w_ih_f;
    const float* __restrict__ w_hh = dir ? w_hh_r : w_hh_f;
    const float* __restrict__ b_ih = dir ? b_ih_r : b_ih_f;
    const float* __restrict__ b_hh = dir ? b_hh_r : b_hh_f;

    const bool valid = (lane < HH);
    const int  j     = valid ? lane : (HH - 1);   // clamp keeps loads in-bounds

    // Row scale per gate (i,f,g,o): sigmoid rows -log2e, tanh row -2log2e.
    const float gsc[4] = { -LOG2E, -LOG2E, -2.0f * LOG2E, -LOG2E };

    // Weights in registers, pre-scaled (v_pk_fma_f32 targets).
    f2 whh[4][10], wih[4][5];
    float bs[4];
#pragma unroll
    for (int g = 0; g < 4; ++g) {
        const int r = g * HH + j;
#pragma unroll
        for (int k = 0; k < 10; ++k) {
            f2 w = *(const f2*)(w_hh + r * HH + 2 * k);
            whh[g][k] = w * gsc[g];
        }
#pragma unroll
        for (int k = 0; k < 5; ++k) {
            f2 w = *(const f2*)(w_ih + r * II + 2 * k);
            wih[g][k] = w * gsc[g];
        }
        bs[g] = (b_ih[r] + b_hh[r]) * gsc[g];
    }

    __shared__ float hstage[CH][HH];   // h history: [step-in-chunk][unit]

    const int t0    = dir ? (TT - 1) : 0;
    const int xstep = dir ? -(BB * II) : (BB * II);
    const int ostep = dir ? -(BB * 2 * HH) : (BB * 2 * HH);
    const int xbase = (t0 * BB + s) * II;

    // Output dump mapping: 320 elements (16 t x 20 j) over 64 lanes x 5.
    const int obase = (t0 * BB + s) * (2 * HH) + dir * HH;
    int offd[5], tdq[5], jdq[5];
#pragma unroll
    for (int q = 0; q < 5; ++q) {
        const int idx = q * 64 + lane;       // 0..319
        tdq[q] = idx / HH;                   // 0..15
        jdq[q] = idx - tdq[q] * HH;          // 0..19
        offd[q] = obase + tdq[q] * ostep + jdq[q];
    }

    // ---- prime the 4-deep x pipeline + xproj(0) ----
    f2 xb1[5], xb2[5], xb3[5];
    float xp[4];
    {
        f2 x0[5];
#pragma unroll
        for (int k = 0; k < 5; ++k) x0[k]  = *(const f2*)(x + xbase + 2 * k);
#pragma unroll
        for (int k = 0; k < 5; ++k) xb1[k] = *(const f2*)(x + xbase + xstep + 2 * k);
#pragma unroll
        for (int k = 0; k < 5; ++k) xb2[k] = *(const f2*)(x + xbase + 2 * xstep + 2 * k);
#pragma unroll
        for (int k = 0; k < 5; ++k) xb3[k] = *(const f2*)(x + xbase + 3 * xstep + 2 * k);
#pragma unroll
        for (int g = 0; g < 4; ++g) {
            f2 p = {bs[g], 0.f};
#pragma unroll
            for (int k = 0; k < 5; ++k) p += wih[g][k] * x0[k];
            xp[g] = p[0] + p[1];
        }
    }
    int xoff4 = xbase + 4 * xstep;   // offset of logical step t+4

    f4 hb[5];
#pragma unroll
    for (int k = 0; k < 5; ++k) hb[k] = f4{0.f, 0.f, 0.f, 0.f};

    float c = 0.0f, h = 0.0f;
    int t = 0;

    for (int chunk = 0; chunk < NCHUNK; ++chunk) {
#pragma unroll
        for (int i = 0; i < CH; ++i, ++t) {
            // ---- recurrent dots: 4 gates x 10 pk-FMA, seeded with xproj ----
            f2 a0[4], a1[4];
#pragma unroll
            for (int g = 0; g < 4; ++g) { a0[g] = f2{xp[g], 0.f}; a1[g] = f2{0.f, 0.f}; }
#pragma unroll
            for (int k = 0; k < 5; ++k) {
                const f4 hv = hb[k];
                f2 lo; lo[0] = hv[0]; lo[1] = hv[1];
                f2 hi; hi[0] = hv[2]; hi[1] = hv[3];
#pragma unroll
                for (int g = 0; g < 4; ++g) {
                    a0[g] += whh[g][2 * k]     * lo;
                    a1[g] += whh[g][2 * k + 1] * hi;
                }
            }
            float u[4];
#pragma unroll
            for (int g = 0; g < 4; ++g) {
                const f2 a = a0[g] + a1[g];
                u[g] = a[0] + a[1];               // pre-scaled: exp2-ready
            }

            // ---- activations, product-rcp form (5 exp2 + 3 rcp) ----
            const float ei = fexp2(u[0]);
            const float ef = fexp2(u[1]);
            const float eg = fexp2(u[2]);
            const float eo = fexp2(u[3]);
            const float fg = __builtin_amdgcn_rcpf(1.0f + ef);             // sigma(v_f)
            const float m  = (1.0f - eg) *
                __builtin_amdgcn_rcpf((1.0f + ei) * (1.0f + eg));          // i*tanh(v_g)
            c = __builtin_fmaf(fg, c, m);
            const float ec = fexp2(c * (-2.0f * LOG2E));
            h = (1.0f - ec) *
                __builtin_amdgcn_rcpf((1.0f + eo) * (1.0f + ec));          // o*tanh(c)

            // ---- stage h + issue broadcast reads for t+1 ----
            if (valid) hstage[i][lane] = h;
            __builtin_amdgcn_wave_barrier();
#pragma unroll
            for (int k = 0; k < 5; ++k)
                hb[k] = *(const f4*)&hstage[i][4 * k];

            // ==== stall-filler: all independent of h ====
            // x load for t+4 (max vmcnt slack)
            f2 xb4[5];
#pragma unroll
            for (int k = 0; k < 5; ++k) xb4[k] = *(const f2*)(x + xoff4 + 2 * k);
            xoff4 += (t < TT - 5) ? xstep : 0;

            // xproj for step t+1 from xb1 (loaded 3 iters ago)
#pragma unroll
            for (int g = 0; g < 4; ++g) {
                f2 p = {bs[g], 0.f};
#pragma unroll
                for (int k = 0; k < 5; ++k) p += wih[g][k] * xb1[k];
                xp[g] = p[0] + p[1];
            }

            // rotate pipeline (renamed away by full unroll)
#pragma unroll
            for (int k = 0; k < 5; ++k) { xb1[k] = xb2[k]; xb2[k] = xb3[k]; xb3[k] = xb4[k]; }
        }

        // ---- dump the chunk's 16x20 h block to HBM (off the chain) ----
        __builtin_amdgcn_wave_barrier();
#pragma unroll
        for (int q = 0; q < 5; ++q) {
            out[offd[q]] = hstage[tdq[q]][jdq[q]];
            offd[q] += CH * ostep;
        }
    }
}

extern "C" void kernel_launch(void* const* d_in, const int* in_sizes, int n_in,
                              void* d_out, int out_size, void* d_ws, size_t ws_size,
                              hipStream_t stream) {
    const float* xp     = (const float*)d_in[0];
    const float* w_ih_f = (const float*)d_in[1];
    const float* w_hh_f = (const float*)d_in[2];
    const float* b_ih_f = (const float*)d_in[3];
    const float* b_hh_f = (const float*)d_in[4];
    const float* w_ih_r = (const float*)d_in[5];
    const float* w_hh_r = (const float*)d_in[6];
    const float* b_ih_r = (const float*)d_in[7];
    const float* b_hh_r = (const float*)d_in[8];
    float* outp = (float*)d_out;

    hipLaunchKernelGGL(lstm_bidir, dim3(1024), dim3(64), 0, stream,
                       xp, w_ih_f, w_hh_f, b_ih_f, b_hh_f,
                       w_ih_r, w_hh_r, b_ih_r, b_hh_r, outp);
}

// Round 14
// 496.472 us; speedup vs baseline: 1.8566x; 1.3028x over previous
//
#include <hip/hip_runtime.h>

typedef float f2 __attribute__((ext_vector_type(2)));
typedef float f4 __attribute__((ext_vector_type(4)));

#define TT 2048
#define BB 512
#define II 10
#define HH 20
#define CH 16                 // consumer steps per barrier / history depth
#define RS 32                 // ring slots = 2 chunks (double buffer)
#define NCHUNK (TT / CH)      // 128

#define LOG2E 1.44269504088896340736f

__device__ __forceinline__ float fexp2(float x) {
#if __has_builtin(__builtin_amdgcn_exp2f)
    return __builtin_amdgcn_exp2f(x);
#else
    return exp2f(x);
#endif
}

// One block = 2 waves per SAMPLE (R10 structure, chain-surgery edition).
// Wave 0 (consumer): lanes 0..19 scan FORWARD, lanes 32..51 scan REVERSE
//   (lane owns hidden unit j of its dir; all 4 gates per lane). Per step:
//   rec dots from hb -> activations -> h -> ds_write -> 5x ds_read_b128.
//   Chain surgery vs R10: (1) ring xp applied LATE (final reduction, not the
//   accumulator seed) so the ring ds_read has ~80cy of rec-FMA slack instead
//   of zero; (2) product-rcp activations (4 exp2 + 3 rcp); (3) cs-prescale:
//   cs = -2log2e*c maintained directly via fma, removing the serial mul
//   before the tanh(c) exp2.
// Wave 1 (producer): xproj[t] = b + W_ih x[t] (pre-scaled) into ring[32][64],
//   double-buffered, 1 __syncthreads per 16 steps.
// Chunk-end: staged 2x16x20 h block dumped to HBM by all 64 lanes.
__global__ __launch_bounds__(128, 1) void lstm_bidir(
    const float* __restrict__ x,
    const float* __restrict__ w_ih_f, const float* __restrict__ w_hh_f,
    const float* __restrict__ b_ih_f, const float* __restrict__ b_hh_f,
    const float* __restrict__ w_ih_r, const float* __restrict__ w_hh_r,
    const float* __restrict__ b_ih_r, const float* __restrict__ b_hh_r,
    float* __restrict__ out)
{
    const int tid  = threadIdx.x;
    const int wid  = tid >> 6;     // 0 = consumer, 1 = producer
    const int lane = tid & 63;
    const int s    = blockIdx.x;   // batch sample

    const int  dirh  = lane >> 5;          // 0 = forward half, 1 = reverse half
    const int  hl    = lane & 31;
    const bool valid = (hl < HH);
    const int  j     = valid ? hl : (HH - 1);   // clamp keeps loads in-bounds

    const float* __restrict__ w_ih = dirh ? w_ih_r : w_ih_f;
    const float* __restrict__ w_hh = dirh ? w_hh_r : w_hh_f;
    const float* __restrict__ b_ih = dirh ? b_ih_r : b_ih_f;
    const float* __restrict__ b_hh = dirh ? b_hh_r : b_hh_f;

    const int t0    = dirh ? (TT - 1) : 0;
    const int xstep = dirh ? -(BB * II) : (BB * II);
    const int ostep = dirh ? -(BB * 2 * HH) : (BB * 2 * HH);
    const int xbase = (t0 * BB + s) * II;

    // Row scale per gate (i,f,g,o): sigmoid rows -log2e, tanh row -2log2e.
    const float gsc[4] = { -LOG2E, -LOG2E, -2.0f * LOG2E, -LOG2E };

    __shared__ f4    ring[RS][64];       // xproj ring: [slot][lane]
    __shared__ float hstage[CH * 64];    // h history: [step-in-chunk][lane]

    if (wid == 1) {
        // ---------------- producer wave (identical to R10) ----------------
        f2 wih[4][5];
        float bs[4];
#pragma unroll
        for (int g = 0; g < 4; ++g) {
            const int r = g * HH + j;
#pragma unroll
            for (int k = 0; k < 5; ++k) {
                f2 w = *(const f2*)(w_ih + r * II + 2 * k);
                wih[g][k] = w * gsc[g];
            }
            bs[g] = (b_ih[r] + b_hh[r]) * gsc[g];
        }

        auto produce8 = [&](int base) {
            f2 xb[8][5];
#pragma unroll
            for (int i = 0; i < 8; ++i) {
                int u = base + i; if (u > TT - 1) u = TT - 1;   // in-bounds clamp
                const float* px = x + (xbase + u * xstep);
#pragma unroll
                for (int k = 0; k < 5; ++k) xb[i][k] = *(const f2*)(px + 2 * k);
            }
#pragma unroll
            for (int i = 0; i < 8; ++i) {
                const int u = base + i;
                if (u < TT) {
                    f4 xp;
#pragma unroll
                    for (int g = 0; g < 4; ++g) {
                        f2 p = {bs[g], 0.f};
#pragma unroll
                        for (int k = 0; k < 5; ++k) p += wih[g][k] * xb[i][k];
                        xp[g] = p[0] + p[1];
                    }
                    ring[u & (RS - 1)][lane] = xp;
                }
            }
        };

        produce8(0);              // prefill steps 0..15
        produce8(8);
        for (int chunk = 0; chunk < NCHUNK; ++chunk) {
            __syncthreads();
            const int base = (chunk + 1) * CH;   // fill next chunk's half
            produce8(base);
            produce8(base + 8);
        }
    } else {
        // ---------------- consumer wave (two scans, one per half) ----------------
        __builtin_amdgcn_s_setprio(1);

        f2 whh[4][10];
#pragma unroll
        for (int g = 0; g < 4; ++g) {
            const int r = g * HH + j;
#pragma unroll
            for (int k = 0; k < 10; ++k) {
                f2 w = *(const f2*)(w_hh + r * HH + 2 * k);
                whh[g][k] = w * gsc[g];
            }
        }

        // Dump mapping: per half, 320 elements (16 t x 20 j) over 32 lanes x 10.
        const int obase = (t0 * BB + s) * (2 * HH) + dirh * HH;
        int offd[10], lds_d[10];
#pragma unroll
        for (int q = 0; q < 10; ++q) {
            const int idx = q * 32 + hl;         // 0..319 within own half
            const int td  = idx / HH;            // 0..15
            const int jd  = idx - td * HH;       // 0..19
            offd[q]  = obase + td * ostep + jd;
            lds_d[q] = td * 64 + dirh * 32 + jd; // own half's row segment
        }

        const int hboff = dirh * 32;             // float offset of own half's h row

        const float K2 = 2.0f * LOG2E;

        f4 hb[5];
#pragma unroll
        for (int k = 0; k < 5; ++k) hb[k] = f4{0.f, 0.f, 0.f, 0.f};

        float cs = 0.0f;    // cs = -2*log2e * c  (so e^{-2c} = 2^cs)
        int t = 0;

        for (int chunk = 0; chunk < NCHUNK; ++chunk) {
            __syncthreads();
            f4 xp = ring[t & (RS - 1)][lane];   // first step of chunk
#pragma unroll
            for (int i = 0; i < CH; ++i, ++t) {
                // ---- recurrent dots: 4 gates x 10 pk-FMA (hb-dependent only) ----
                f2 a0[4], a1[4];
#pragma unroll
                for (int g = 0; g < 4; ++g) { a0[g] = f2{0.f, 0.f}; a1[g] = f2{0.f, 0.f}; }
#pragma unroll
                for (int k = 0; k < 5; ++k) {
                    const f4 hv = hb[k];
                    f2 lo; lo[0] = hv[0]; lo[1] = hv[1];
                    f2 hi; hi[0] = hv[2]; hi[1] = hv[3];
#pragma unroll
                    for (int g = 0; g < 4; ++g) {
                        a0[g] += whh[g][2 * k]     * lo;
                        a1[g] += whh[g][2 * k + 1] * hi;
                    }
                }
                // xp applied LATE: ring ds_read gets ~80cy of rec-FMA slack.
                float u[4];
#pragma unroll
                for (int g = 0; g < 4; ++g) {
                    const f2 a = a0[g] + a1[g];
                    u[g] = (xp[g] + a[0]) + a[1];   // pre-scaled: exp2-ready
                }

                // ---- activations, product-rcp + cs fold (4 exp2 + 3 rcp) ----
                const float ei = fexp2(u[0]);
                const float ef = fexp2(u[1]);
                const float eg = fexp2(u[2]);
                const float eo = fexp2(u[3]);
                const float fg = __builtin_amdgcn_rcpf(1.0f + ef);           // sigma(v_f)
                const float r1 = __builtin_amdgcn_rcpf((1.0f + ei) * (1.0f + eg));
                const float km = __builtin_fmaf(K2, eg, -K2) * r1;  // -2log2e * i*tanh(v_g)
                cs = __builtin_fmaf(fg, cs, km);                    // -2log2e * c
                const float ec = fexp2(cs);                         // e^{-2c}
                const float h  = (1.0f - ec) *
                    __builtin_amdgcn_rcpf((1.0f + eo) * (1.0f + ec));        // o*tanh(c)

                // ---- stage h (unconditional; clamp-lanes write unread slots) ----
                hstage[i * 64 + lane] = h;
                __builtin_amdgcn_wave_barrier();

                // ---- broadcast read of own half's 20 h (same-wave LDS in-order) ----
#pragma unroll
                for (int k = 0; k < 5; ++k)
                    hb[k] = *(const f4*)&hstage[i * 64 + hboff + 4 * k];

                // ---- ring read for next step (consumed late next iter) ----
                if (i < CH - 1) xp = ring[(t + 1) & (RS - 1)][lane];
            }

            // ---- dump the chunk's 2x16x20 h block to HBM (off the chain) ----
#pragma unroll
            for (int q = 0; q < 10; ++q) {
                const float v = hstage[lds_d[q]];
                out[offd[q]] = v;
                offd[q] += CH * ostep;
            }
        }
    }
}

extern "C" void kernel_launch(void* const* d_in, const int* in_sizes, int n_in,
                              void* d_out, int out_size, void* d_ws, size_t ws_size,
                              hipStream_t stream) {
    const float* xp     = (const float*)d_in[0];
    const float* w_ih_f = (const float*)d_in[1];
    const float* w_hh_f = (const float*)d_in[2];
    const float* b_ih_f = (const float*)d_in[3];
    const float* b_hh_f = (const float*)d_in[4];
    const float* w_ih_r = (const float*)d_in[5];
    const float* w_hh_r = (const float*)d_in[6];
    const float* b_ih_r = (const float*)d_in[7];
    const float* b_hh_r = (const float*)d_in[8];
    float* outp = (float*)d_out;

    hipLaunchKernelGGL(lstm_bidir, dim3(512), dim3(128), 0, stream,
                       xp, w_ih_f, w_hh_f, b_ih_f, b_hh_f,
                       w_ih_r, w_hh_r, b_ih_r, b_hh_r, outp);
}

// Round 15
// 470.068 us; speedup vs baseline: 1.9608x; 1.0562x over previous
//
#include <hip/hip_runtime.h>

typedef float f2 __attribute__((ext_vector_type(2)));
typedef float f4 __attribute__((ext_vector_type(4)));

#define TT 2048
#define BB 512
#define II 10
#define HH 20
#define CH 16                 // consumer steps per barrier / history depth
#define RS 32                 // ring slots = 2 chunks (double buffer)
#define NCHUNK (TT / CH)      // 128

#define LOG2E 1.44269504088896340736f

__device__ __forceinline__ float fexp2(float x) {
#if __has_builtin(__builtin_amdgcn_exp2f)
    return __builtin_amdgcn_exp2f(x);
#else
    return exp2f(x);
#endif
}

// One block = 2 waves per SAMPLE (R14 structure, micro-tuned).
// Wave 0 (consumer): lanes 0..19 scan FORWARD, lanes 32..51 scan REVERSE
//   (lane owns hidden unit j of its dir; all 4 gates per lane). Per step:
//   rec dots from hb -> ring xp applied LATE -> product-rcp activations
//   (4 exp2 + 3 rcp) with cs = -2log2e*c maintained via fma -> h ->
//   ds_write -> 5x ds_read_b128 broadcast.
// Wave 1 (producer): xproj[t] = b + W_ih x[t] (pre-scaled) into ring[32][64],
//   double-buffered, 1 __syncthreads per 16 steps.
// Chunk-end: staged 2x16x20 h block dumped to HBM by all 64 lanes.
// R15 deltas: inner loop at #pragma unroll 4 (was full 16: ~11KB body ->
// ~3KB, removes any I-fetch component); branchless ring prefetch (last-iter
// read races with producer but is discarded and re-read after the barrier).
__global__ __launch_bounds__(128, 1) void lstm_bidir(
    const float* __restrict__ x,
    const float* __restrict__ w_ih_f, const float* __restrict__ w_hh_f,
    const float* __restrict__ b_ih_f, const float* __restrict__ b_hh_f,
    const float* __restrict__ w_ih_r, const float* __restrict__ w_hh_r,
    const float* __restrict__ b_ih_r, const float* __restrict__ b_hh_r,
    float* __restrict__ out)
{
    const int tid  = threadIdx.x;
    const int wid  = tid >> 6;     // 0 = consumer, 1 = producer
    const int lane = tid & 63;
    const int s    = blockIdx.x;   // batch sample

    const int  dirh  = lane >> 5;          // 0 = forward half, 1 = reverse half
    const int  hl    = lane & 31;
    const bool valid = (hl < HH);
    const int  j     = valid ? hl : (HH - 1);   // clamp keeps loads in-bounds

    const float* __restrict__ w_ih = dirh ? w_ih_r : w_ih_f;
    const float* __restrict__ w_hh = dirh ? w_hh_r : w_hh_f;
    const float* __restrict__ b_ih = dirh ? b_ih_r : b_ih_f;
    const float* __restrict__ b_hh = dirh ? b_hh_r : b_hh_f;

    const int t0    = dirh ? (TT - 1) : 0;
    const int xstep = dirh ? -(BB * II) : (BB * II);
    const int ostep = dirh ? -(BB * 2 * HH) : (BB * 2 * HH);
    const int xbase = (t0 * BB + s) * II;

    // Row scale per gate (i,f,g,o): sigmoid rows -log2e, tanh row -2log2e.
    const float gsc[4] = { -LOG2E, -LOG2E, -2.0f * LOG2E, -LOG2E };

    __shared__ f4    ring[RS][64];       // xproj ring: [slot][lane]
    __shared__ float hstage[CH * 64];    // h history: [step-in-chunk][lane]

    if (wid == 1) {
        // ---------------- producer wave (identical to R14) ----------------
        f2 wih[4][5];
        float bs[4];
#pragma unroll
        for (int g = 0; g < 4; ++g) {
            const int r = g * HH + j;
#pragma unroll
            for (int k = 0; k < 5; ++k) {
                f2 w = *(const f2*)(w_ih + r * II + 2 * k);
                wih[g][k] = w * gsc[g];
            }
            bs[g] = (b_ih[r] + b_hh[r]) * gsc[g];
        }

        auto produce8 = [&](int base) {
            f2 xb[8][5];
#pragma unroll
            for (int i = 0; i < 8; ++i) {
                int u = base + i; if (u > TT - 1) u = TT - 1;   // in-bounds clamp
                const float* px = x + (xbase + u * xstep);
#pragma unroll
                for (int k = 0; k < 5; ++k) xb[i][k] = *(const f2*)(px + 2 * k);
            }
#pragma unroll
            for (int i = 0; i < 8; ++i) {
                const int u = base + i;
                if (u < TT) {
                    f4 xp;
#pragma unroll
                    for (int g = 0; g < 4; ++g) {
                        f2 p = {bs[g], 0.f};
#pragma unroll
                        for (int k = 0; k < 5; ++k) p += wih[g][k] * xb[i][k];
                        xp[g] = p[0] + p[1];
                    }
                    ring[u & (RS - 1)][lane] = xp;
                }
            }
        };

        produce8(0);              // prefill steps 0..15
        produce8(8);
        for (int chunk = 0; chunk < NCHUNK; ++chunk) {
            __syncthreads();
            const int base = (chunk + 1) * CH;   // fill next chunk's half
            produce8(base);
            produce8(base + 8);
        }
    } else {
        // ---------------- consumer wave (two scans, one per half) ----------------
        __builtin_amdgcn_s_setprio(1);

        f2 whh[4][10];
#pragma unroll
        for (int g = 0; g < 4; ++g) {
            const int r = g * HH + j;
#pragma unroll
            for (int k = 0; k < 10; ++k) {
                f2 w = *(const f2*)(w_hh + r * HH + 2 * k);
                whh[g][k] = w * gsc[g];
            }
        }

        // Dump mapping: per half, 320 elements (16 t x 20 j) over 32 lanes x 10.
        const int obase = (t0 * BB + s) * (2 * HH) + dirh * HH;
        int offd[10], lds_d[10];
#pragma unroll
        for (int q = 0; q < 10; ++q) {
            const int idx = q * 32 + hl;         // 0..319 within own half
            const int td  = idx / HH;            // 0..15
            const int jd  = idx - td * HH;       // 0..19
            offd[q]  = obase + td * ostep + jd;
            lds_d[q] = td * 64 + dirh * 32 + jd; // own half's row segment
        }

        const int hboff = dirh * 32;             // float offset of own half's h row

        const float K2 = 2.0f * LOG2E;

        f4 hb[5];
#pragma unroll
        for (int k = 0; k < 5; ++k) hb[k] = f4{0.f, 0.f, 0.f, 0.f};

        float cs = 0.0f;    // cs = -2*log2e * c  (so e^{-2c} = 2^cs)
        int t = 0;

        for (int chunk = 0; chunk < NCHUNK; ++chunk) {
            __syncthreads();
            f4 xp = ring[t & (RS - 1)][lane];   // first step of chunk
#pragma unroll 4
            for (int i = 0; i < CH; ++i, ++t) {
                // ---- recurrent dots: 4 gates x 10 pk-FMA (hb-dependent only) ----
                f2 a0[4], a1[4];
#pragma unroll
                for (int g = 0; g < 4; ++g) { a0[g] = f2{0.f, 0.f}; a1[g] = f2{0.f, 0.f}; }
#pragma unroll
                for (int k = 0; k < 5; ++k) {
                    const f4 hv = hb[k];
                    f2 lo; lo[0] = hv[0]; lo[1] = hv[1];
                    f2 hi; hi[0] = hv[2]; hi[1] = hv[3];
#pragma unroll
                    for (int g = 0; g < 4; ++g) {
                        a0[g] += whh[g][2 * k]     * lo;
                        a1[g] += whh[g][2 * k + 1] * hi;
                    }
                }
                // xp applied LATE: ring ds_read gets ~80cy of rec-FMA slack.
                float u[4];
#pragma unroll
                for (int g = 0; g < 4; ++g) {
                    const f2 a = a0[g] + a1[g];
                    u[g] = (xp[g] + a[0]) + a[1];   // pre-scaled: exp2-ready
                }

                // ---- activations, product-rcp + cs fold (4 exp2 + 3 rcp) ----
                const float ei = fexp2(u[0]);
                const float ef = fexp2(u[1]);
                const float eg = fexp2(u[2]);
                const float eo = fexp2(u[3]);
                const float fg = __builtin_amdgcn_rcpf(1.0f + ef);           // sigma(v_f)
                const float r1 = __builtin_amdgcn_rcpf((1.0f + ei) * (1.0f + eg));
                const float km = __builtin_fmaf(K2, eg, -K2) * r1;  // -2log2e * i*tanh(v_g)
                cs = __builtin_fmaf(fg, cs, km);                    // -2log2e * c
                const float ec = fexp2(cs);                         // e^{-2c}
                const float h  = (1.0f - ec) *
                    __builtin_amdgcn_rcpf((1.0f + eo) * (1.0f + ec));        // o*tanh(c)

                // ---- stage h (unconditional; clamp-lanes write unread slots) ----
                hstage[i * 64 + lane] = h;
                __builtin_amdgcn_wave_barrier();

                // ---- broadcast read of own half's 20 h (same-wave LDS in-order) ----
#pragma unroll
                for (int k = 0; k < 5; ++k)
                    hb[k] = *(const f4*)&hstage[i * 64 + hboff + 4 * k];

                // ---- ring read for next step, branchless (last-iter value is
                //      discarded and re-read after the chunk barrier; the
                //      concurrent producer write it races with is benign) ----
                xp = ring[(t + 1) & (RS - 1)][lane];
            }

            // ---- dump the chunk's 2x16x20 h block to HBM (off the chain) ----
#pragma unroll
            for (int q = 0; q < 10; ++q) {
                const float v = hstage[lds_d[q]];
                out[offd[q]] = v;
                offd[q] += CH * ostep;
            }
        }
    }
}

extern "C" void kernel_launch(void* const* d_in, const int* in_sizes, int n_in,
                              void* d_out, int out_size, void* d_ws, size_t ws_size,
                              hipStream_t stream) {
    const float* xp     = (const float*)d_in[0];
    const float* w_ih_f = (const float*)d_in[1];
    const float* w_hh_f = (const float*)d_in[2];
    const float* b_ih_f = (const float*)d_in[3];
    const float* b_hh_f = (const float*)d_in[4];
    const float* w_ih_r = (const float*)d_in[5];
    const float* w_hh_r = (const float*)d_in[6];
    const float* b_ih_r = (const float*)d_in[7];
    const float* b_hh_r = (const float*)d_in[8];
    float* outp = (float*)d_out;

    hipLaunchKernelGGL(lstm_bidir, dim3(512), dim3(128), 0, stream,
                       xp, w_ih_f, w_hh_f, b_ih_f, b_hh_f,
                       w_ih_r, w_hh_r, b_ih_r, b_hh_r, outp);
}

// Round 16
// 441.203 us; speedup vs baseline: 2.0891x; 1.0654x over previous
//
#include <hip/hip_runtime.h>

typedef float f2 __attribute__((ext_vector_type(2)));
typedef float f4 __attribute__((ext_vector_type(4)));

#define TT 2048
#define BB 512
#define II 10
#define HH 20
#define CH 32                 // consumer steps per barrier / history depth
#define RS 64                 // ring slots = 2 chunks (double buffer)
#define NCHUNK (TT / CH)      // 64

#define LOG2E 1.44269504088896340736f

__device__ __forceinline__ float fexp2(float x) {
#if __has_builtin(__builtin_amdgcn_exp2f)
    return __builtin_amdgcn_exp2f(x);
#else
    return exp2f(x);
#endif
}

// One block = 2 waves per SAMPLE (R15 structure, barrier/queue-slop probe).
// Wave 0 (consumer): lanes 0..19 scan FORWARD, lanes 32..51 scan REVERSE
//   (lane owns hidden unit j of its dir; all 4 gates per lane). Per step:
//   rec dots from hb -> ring xp applied LATE -> product-rcp activations
//   (4 exp2 + 3 rcp) with cs = -2log2e*c maintained via fma -> h ->
//   ring prefetch read -> ds_write h -> 5x ds_read_b128 broadcast.
// Wave 1 (producer): xproj[t] = b + W_ih x[t] (pre-scaled) into ring[64][64],
//   double-buffered halves, 1 __syncthreads per 32 steps.
// R16 deltas vs R15: CH=32 (half the barriers; ring 64KB, still 2 blocks/CU),
// ring read issued BEFORE the h-write (LDS queue [ring, write, hb x5] so hb's
// granular lgkmcnt waits don't sit behind the ring read), dump 20 elems/lane.
__global__ __launch_bounds__(128, 1) void lstm_bidir(
    const float* __restrict__ x,
    const float* __restrict__ w_ih_f, const float* __restrict__ w_hh_f,
    const float* __restrict__ b_ih_f, const float* __restrict__ b_hh_f,
    const float* __restrict__ w_ih_r, const float* __restrict__ w_hh_r,
    const float* __restrict__ b_ih_r, const float* __restrict__ b_hh_r,
    float* __restrict__ out)
{
    const int tid  = threadIdx.x;
    const int wid  = tid >> 6;     // 0 = consumer, 1 = producer
    const int lane = tid & 63;
    const int s    = blockIdx.x;   // batch sample

    const int  dirh  = lane >> 5;          // 0 = forward half, 1 = reverse half
    const int  hl    = lane & 31;
    const bool valid = (hl < HH);
    const int  j     = valid ? hl : (HH - 1);   // clamp keeps loads in-bounds

    const float* __restrict__ w_ih = dirh ? w_ih_r : w_ih_f;
    const float* __restrict__ w_hh = dirh ? w_hh_r : w_hh_f;
    const float* __restrict__ b_ih = dirh ? b_ih_r : b_ih_f;
    const float* __restrict__ b_hh = dirh ? b_hh_r : b_hh_f;

    const int t0    = dirh ? (TT - 1) : 0;
    const int xstep = dirh ? -(BB * II) : (BB * II);
    const int ostep = dirh ? -(BB * 2 * HH) : (BB * 2 * HH);
    const int xbase = (t0 * BB + s) * II;

    // Row scale per gate (i,f,g,o): sigmoid rows -log2e, tanh row -2log2e.
    const float gsc[4] = { -LOG2E, -LOG2E, -2.0f * LOG2E, -LOG2E };

    __shared__ f4    ring[RS][64];       // xproj ring: [slot][lane]
    __shared__ float hstage[CH * 64];    // h history: [step-in-chunk][lane]

    if (wid == 1) {
        // ---------------- producer wave ----------------
        f2 wih[4][5];
        float bs[4];
#pragma unroll
        for (int g = 0; g < 4; ++g) {
            const int r = g * HH + j;
#pragma unroll
            for (int k = 0; k < 5; ++k) {
                f2 w = *(const f2*)(w_ih + r * II + 2 * k);
                wih[g][k] = w * gsc[g];
            }
            bs[g] = (b_ih[r] + b_hh[r]) * gsc[g];
        }

        auto produce8 = [&](int base) {
            f2 xb[8][5];
#pragma unroll
            for (int i = 0; i < 8; ++i) {
                int u = base + i; if (u > TT - 1) u = TT - 1;   // in-bounds clamp
                const float* px = x + (xbase + u * xstep);
#pragma unroll
                for (int k = 0; k < 5; ++k) xb[i][k] = *(const f2*)(px + 2 * k);
            }
#pragma unroll
            for (int i = 0; i < 8; ++i) {
                const int u = base + i;
                if (u < TT) {
                    f4 xp;
#pragma unroll
                    for (int g = 0; g < 4; ++g) {
                        f2 p = {bs[g], 0.f};
#pragma unroll
                        for (int k = 0; k < 5; ++k) p += wih[g][k] * xb[i][k];
                        xp[g] = p[0] + p[1];
                    }
                    ring[u & (RS - 1)][lane] = xp;
                }
            }
        };

        produce8(0);  produce8(8);     // prefill steps 0..31
        produce8(16); produce8(24);
        for (int chunk = 0; chunk < NCHUNK; ++chunk) {
            __syncthreads();
            const int base = (chunk + 1) * CH;   // fill next chunk's half
            produce8(base);      produce8(base + 8);
            produce8(base + 16); produce8(base + 24);
        }
    } else {
        // ---------------- consumer wave (two scans, one per half) ----------------
        __builtin_amdgcn_s_setprio(1);

        f2 whh[4][10];
#pragma unroll
        for (int g = 0; g < 4; ++g) {
            const int r = g * HH + j;
#pragma unroll
            for (int k = 0; k < 10; ++k) {
                f2 w = *(const f2*)(w_hh + r * HH + 2 * k);
                whh[g][k] = w * gsc[g];
            }
        }

        // Dump mapping: per half, 640 elements (32 t x 20 j) over 32 lanes x 20.
        const int obase = (t0 * BB + s) * (2 * HH) + dirh * HH;
        int offd[20], lds_d[20];
#pragma unroll
        for (int q = 0; q < 20; ++q) {
            const int idx = q * 32 + hl;         // 0..639 within own half
            const int td  = idx / HH;            // 0..31
            const int jd  = idx - td * HH;       // 0..19
            offd[q]  = obase + td * ostep + jd;
            lds_d[q] = td * 64 + dirh * 32 + jd; // own half's row segment
        }

        const int hboff = dirh * 32;             // float offset of own half's h row

        const float K2 = 2.0f * LOG2E;

        f4 hb[5];
#pragma unroll
        for (int k = 0; k < 5; ++k) hb[k] = f4{0.f, 0.f, 0.f, 0.f};

        float cs = 0.0f;    // cs = -2*log2e * c  (so e^{-2c} = 2^cs)
        int t = 0;

        for (int chunk = 0; chunk < NCHUNK; ++chunk) {
            __syncthreads();
            f4 xp = ring[t & (RS - 1)][lane];   // first step of chunk
#pragma unroll 4
            for (int i = 0; i < CH; ++i, ++t) {
                // ---- recurrent dots: 4 gates x 10 pk-FMA (hb-dependent only) ----
                f2 a0[4], a1[4];
#pragma unroll
                for (int g = 0; g < 4; ++g) { a0[g] = f2{0.f, 0.f}; a1[g] = f2{0.f, 0.f}; }
#pragma unroll
                for (int k = 0; k < 5; ++k) {
                    const f4 hv = hb[k];
                    f2 lo; lo[0] = hv[0]; lo[1] = hv[1];
                    f2 hi; hi[0] = hv[2]; hi[1] = hv[3];
#pragma unroll
                    for (int g = 0; g < 4; ++g) {
                        a0[g] += whh[g][2 * k]     * lo;
                        a1[g] += whh[g][2 * k + 1] * hi;
                    }
                }
                // xp applied LATE: ring ds_read gets ~80cy of rec-FMA slack.
                float u[4];
#pragma unroll
                for (int g = 0; g < 4; ++g) {
                    const f2 a = a0[g] + a1[g];
                    u[g] = (xp[g] + a[0]) + a[1];   // pre-scaled: exp2-ready
                }

                // ---- activations, product-rcp + cs fold (4 exp2 + 3 rcp) ----
                const float ei = fexp2(u[0]);
                const float ef = fexp2(u[1]);
                const float eg = fexp2(u[2]);
                const float eo = fexp2(u[3]);
                const float fg = __builtin_amdgcn_rcpf(1.0f + ef);           // sigma(v_f)
                const float r1 = __builtin_amdgcn_rcpf((1.0f + ei) * (1.0f + eg));
                const float km = __builtin_fmaf(K2, eg, -K2) * r1;  // -2log2e * i*tanh(v_g)
                cs = __builtin_fmaf(fg, cs, km);                    // -2log2e * c
                const float ec = fexp2(cs);                         // e^{-2c}
                const float h  = (1.0f - ec) *
                    __builtin_amdgcn_rcpf((1.0f + eo) * (1.0f + ec));        // o*tanh(c)

                // ---- ring prefetch FIRST (LDS queue: [ring, write, hb x5]) ----
                xp = ring[(t + 1) & (RS - 1)][lane];   // last-iter race benign

                // ---- stage h (unconditional; clamp-lanes write unread slots) ----
                hstage[i * 64 + lane] = h;
                __builtin_amdgcn_wave_barrier();

                // ---- broadcast read of own half's 20 h (same-wave LDS in-order) ----
#pragma unroll
                for (int k = 0; k < 5; ++k)
                    hb[k] = *(const f4*)&hstage[i * 64 + hboff + 4 * k];
            }

            // ---- dump the chunk's 2x32x20 h block to HBM (off the chain) ----
#pragma unroll
            for (int q = 0; q < 20; ++q) {
                const float v = hstage[lds_d[q]];
                out[offd[q]] = v;
                offd[q] += CH * ostep;
            }
        }
    }
}

extern "C" void kernel_launch(void* const* d_in, const int* in_sizes, int n_in,
                              void* d_out, int out_size, void* d_ws, size_t ws_size,
                              hipStream_t stream) {
    const float* xp     = (const float*)d_in[0];
    const float* w_ih_f = (const float*)d_in[1];
    const float* w_hh_f = (const float*)d_in[2];
    const float* b_ih_f = (const float*)d_in[3];
    const float* b_hh_f = (const float*)d_in[4];
    const float* w_ih_r = (const float*)d_in[5];
    const float* w_hh_r = (const float*)d_in[6];
    const float* b_ih_r = (const float*)d_in[7];
    const float* b_hh_r = (const float*)d_in[8];
    float* outp = (float*)d_out;

    hipLaunchKernelGGL(lstm_bidir, dim3(512), dim3(128), 0, stream,
                       xp, w_ih_f, w_hh_f, b_ih_f, b_hh_f,
                       w_ih_r, w_hh_r, b_ih_r, b_hh_r, outp);
}